// Round 5
// baseline (274.233 us; speedup 1.0000x reference)
//
#include <hip/hip_runtime.h>
#include <stdint.h>

// Problem sizes (fixed by reference)
constexpr int Bb = 8;      // batch
constexpr int Ss = 2048;   // sequence
constexpr int Dd = 1024;   // model dim (K of GEMM)
constexpr int Oo = 1024;   // expert out dim (N of GEMM)
constexpr int Ee = 8;      // experts

typedef __bf16 bf16x8 __attribute__((ext_vector_type(8)));
typedef float  f32x4  __attribute__((ext_vector_type(4)));

__device__ __forceinline__ unsigned short f2bf(float f) {
  // round-to-nearest-even fp32 -> bf16 (inputs are finite)
  unsigned int u = __float_as_uint(f);
  unsigned int r = (u + 0x7fffu + ((u >> 16) & 1u)) >> 16;
  return (unsigned short)r;
}

__device__ __forceinline__ void gl_lds16(const void* g, void* l) {
  // async 16B global -> LDS; LDS dest is wave-uniform base + lane*16
  __builtin_amdgcn_global_load_lds((const __attribute__((address_space(1))) void*)g,
                                   (__attribute__((address_space(3))) void*)l,
                                   16, 0, 0);
}

// ---------------------------------------------------------------------------
// Kernel A: convert x fp32->bf16 AND accumulate column sums (for mean pool)
// grid: (64, 8) blocks of 256; each block does 32 rows -> 64 atomics/address
// ---------------------------------------------------------------------------
__global__ __launch_bounds__(256) void k_convert_pool(
    const float* __restrict__ x, unsigned short* __restrict__ xb,
    float* __restrict__ pooled) {
  const int b  = blockIdx.y;
  const int sc = blockIdx.x;
  const int t  = threadIdx.x;
  const size_t base = (size_t)b * Ss * Dd + (size_t)sc * 32 * Dd + t * 4;
  const float4* xp = (const float4*)(x + base);
  ushort4* xo = (ushort4*)(xb + base);
  float4 acc = make_float4(0.f, 0.f, 0.f, 0.f);
#pragma unroll 8
  for (int s = 0; s < 32; ++s) {
    float4 v = xp[(size_t)s * (Dd / 4)];
    acc.x += v.x; acc.y += v.y; acc.z += v.z; acc.w += v.w;
    ushort4 o;
    o.x = f2bf(v.x); o.y = f2bf(v.y); o.z = f2bf(v.z); o.w = f2bf(v.w);
    xo[(size_t)s * (Dd / 4)] = o;
  }
  float* pd = pooled + b * Dd + t * 4;
  atomicAdd(pd + 0, acc.x);
  atomicAdd(pd + 1, acc.y);
  atomicAdd(pd + 2, acc.z);
  atomicAdd(pd + 3, acc.w);
}

// ---------------------------------------------------------------------------
// Kernel C: convert expert_w fp32->bf16. 8M elements, exactly covered.
// ---------------------------------------------------------------------------
__global__ __launch_bounds__(256) void k_convert_w(
    const float* __restrict__ w, unsigned short* __restrict__ wb) {
  size_t i = ((size_t)blockIdx.x * 256 + threadIdx.x) * 4;
  float4 v = *(const float4*)(w + i);
  ushort4 o;
  o.x = f2bf(v.x); o.y = f2bf(v.y); o.z = f2bf(v.z); o.w = f2bf(v.w);
  *(ushort4*)(wb + i) = o;
}

// ---------------------------------------------------------------------------
// Kernel B: logits = (pooled/S) @ gate_w^T + gate_b ; compact top-2 selection
// One block, 256 threads. 4 threads per (b,e) pair.
// Emits eidx[b][2] (expert ids) and egate[b][2] (softmax weights over top-2).
// ---------------------------------------------------------------------------
__global__ __launch_bounds__(256) void k_gates(
    const float* __restrict__ pooled, const float* __restrict__ gw,
    const float* __restrict__ gb, int* __restrict__ eidx,
    float* __restrict__ egate) {
  __shared__ float slog[Bb * Ee];
  const int t = threadIdx.x;
  const int p = t >> 2, part = t & 3;
  const int b = p >> 3, e = p & 7;
  const float4* pv = (const float4*)(pooled + b * Dd + part * 256);
  const float4* wv = (const float4*)(gw + e * Dd + part * 256);
  float s = 0.f;
#pragma unroll
  for (int i = 0; i < 64; ++i) {
    float4 a = pv[i], w = wv[i];
    s += a.x * w.x + a.y * w.y + a.z * w.z + a.w * w.w;
  }
  s += __shfl_xor(s, 1);
  s += __shfl_xor(s, 2);
  if (part == 0) slog[p] = s * (1.0f / (float)Ss) + gb[e];
  __syncthreads();
  if (t < Bb) {
    float m1 = -3.4e38f, m2 = -3.4e38f;
    int i1 = 0, i2 = 0;
#pragma unroll
    for (int i = 0; i < Ee; ++i) {
      const float v = slog[t * Ee + i];
      if (v > m1) { m2 = m1; i2 = i1; m1 = v; i1 = i; }
      else if (v > m2) { m2 = v; i2 = i; }
    }
    const float e2 = expf(m2 - m1);
    const float inv = 1.0f / (1.0f + e2);
    eidx[t * 2 + 0] = i1;
    eidx[t * 2 + 1] = i2;
    egate[t * 2 + 0] = inv;
    egate[t * 2 + 1] = e2 * inv;
  }
}

// ---------------------------------------------------------------------------
// Kernel D: fused dual-expert GEMM, counted-vmcnt 2-phase pipeline (T3/T4).
// Tile: BM=128 (s) x BN=64 (o), BK=64, double-buffered LDS (2 x 32KB = 64KB):
//   per stage: A 128x64 (16KB) + B0 64x64 (8KB) + B1 64x64 (8KB).
// 4 waves (2x2); per wave 64x32 output per expert; 32 MFMA per K-step.
// Pipeline: STAGE(next) issued BEFORE compute(cur); s_waitcnt vmcnt(8) waits
// only the PREVIOUS stage's 8 loads; raw s_barrier (no full drain).
// LDS XOR-swizzle via inverse-swizzled global source + swizzled ds_read.
// ---------------------------------------------------------------------------
constexpr int BM = 128, BN = 64, BK = 64;
constexpr int STG = 32768;        // bytes per stage
constexpr int OFF_B0 = 16384, OFF_B1 = 24576;

__global__ __launch_bounds__(256, 2) void k_moe_gemm(
    const unsigned short* __restrict__ xb, const unsigned short* __restrict__ wb,
    const int* __restrict__ eidx, const float* __restrict__ egate,
    const float* __restrict__ expert_b, float* __restrict__ out) {
  __shared__ char lds[2 * STG];   // 64 KB

  // XCD-aware bijective swizzle: 2048 blocks, 8 XCDs -> one batch per XCD.
  const int hw = blockIdx.x;
  const int lg_id = ((hw & 7) << 8) | (hw >> 3);
  const int b  = lg_id >> 8;                // batch == XCD
  const int m0 = (lg_id & 15) * BM;         // s
  const int n0 = ((lg_id >> 4) & 15) * BN;  // o
  const int t  = threadIdx.x;
  const int lane = t & 63;
  const int wid  = t >> 6;
  const int wr = wid >> 1, wc = wid & 1;    // wave -> 64x32 subtile
  const int lr = lane & 15;                 // frag row (A) / col (B,D)
  const int lg = lane >> 4;                 // frag k-group 0..3

  const int e0 = eidx[b * 2 + 0];
  const int e1 = eidx[b * 2 + 1];
  const float g0 = egate[b * 2 + 0];
  const float g1 = egate[b * 2 + 1];

  // staging geometry: thread t writes LDS linear byte t*16 (+h*4096);
  // global source column inverse-swizzled so swizzled reads see logical data
  const int srow = t >> 3;                          // 0..31 (+h*32)
  const int scol = (((t & 7) ^ (srow & 7)) * 8);    // element offset in row
  const int ldsoff = wid * 1024;                    // wave-uniform byte part

  const unsigned short* Abase  = xb + (size_t)b * Ss * Dd + (size_t)m0 * Dd;
  const unsigned short* B0base = wb + (size_t)e0 * Oo * Dd + (size_t)n0 * Dd;
  const unsigned short* B1base = wb + (size_t)e1 * Oo * Dd + (size_t)n0 * Dd;

  f32x4 acc0[4][2] = {};
  f32x4 acc1[4][2] = {};

  // ---- STAGE: issue 8 global_load_lds for K-tile kt into stage st ----
  auto STAGE = [&](int st, int kt) {
    char* base = lds + st * STG;
#pragma unroll
    for (int h = 0; h < 4; ++h) {   // A: 128 rows
      const int row = srow + h * 32;
      gl_lds16(Abase + (size_t)row * Dd + kt + scol,
               base + h * 4096 + ldsoff);
    }
#pragma unroll
    for (int h = 0; h < 2; ++h) {   // B0, B1: 64 rows each
      const int row = srow + h * 32;
      const size_t goff = (size_t)row * Dd + kt + scol;
      gl_lds16(B0base + goff, base + OFF_B0 + h * 4096 + ldsoff);
      gl_lds16(B1base + goff, base + OFF_B1 + h * 4096 + ldsoff);
    }
  };

  // ---- COMPUTE: 16 ds_read_b128 + 32 MFMA on stage st ----
  auto COMPUTE = [&](int st) {
    const char* base = lds + st * STG;
#pragma unroll
    for (int ks = 0; ks < 2; ++ks) {
      const int ul = (ks << 2) | lg;     // logical 16B unit in 128B row
      bf16x8 af[4], bf0[2], bf1[2];
#pragma unroll
      for (int m = 0; m < 4; ++m) {
        const int r = wr * 64 + m * 16 + lr;
        af[m] = *(const bf16x8*)(base + r * 128 + ((ul ^ (r & 7)) << 4));
      }
#pragma unroll
      for (int n = 0; n < 2; ++n) {
        const int r = wc * 32 + n * 16 + lr;
        bf0[n] = *(const bf16x8*)(base + OFF_B0 + r * 128 + ((ul ^ (r & 7)) << 4));
        bf1[n] = *(const bf16x8*)(base + OFF_B1 + r * 128 + ((ul ^ (r & 7)) << 4));
      }
#pragma unroll
      for (int m = 0; m < 4; ++m)
#pragma unroll
        for (int n = 0; n < 2; ++n) {
          acc0[m][n] = __builtin_amdgcn_mfma_f32_16x16x32_bf16(
              af[m], bf0[n], acc0[m][n], 0, 0, 0);
          acc1[m][n] = __builtin_amdgcn_mfma_f32_16x16x32_bf16(
              af[m], bf1[n], acc1[m][n], 0, 0, 0);
        }
    }
  };

  // ---- pipelined K loop: 16 K-steps ----
  STAGE(0, 0);
  int cur = 0;
#pragma unroll 1
  for (int kt_i = 0; kt_i < 15; ++kt_i) {
    STAGE(cur ^ 1, (kt_i + 1) * BK);                 // prefetch next (8 loads)
    asm volatile("s_waitcnt vmcnt(8)" ::: "memory"); // wait only cur's loads
    __builtin_amdgcn_s_barrier();
    __builtin_amdgcn_sched_barrier(0);
    COMPUTE(cur);
    __builtin_amdgcn_s_barrier();                    // protect buf reuse
    __builtin_amdgcn_sched_barrier(0);
    cur ^= 1;
  }
  asm volatile("s_waitcnt vmcnt(0)" ::: "memory");
  __builtin_amdgcn_s_barrier();
  __builtin_amdgcn_sched_barrier(0);
  COMPUTE(cur);

  // epilogue: out = g0*gelu(acc0+bias0) + g1*gelu(acc1+bias1), single store
#pragma unroll
  for (int n = 0; n < 2; ++n) {
    const int col = n0 + wc * 32 + n * 16 + lr;
    const float bias0 = expert_b[e0 * Oo + col];
    const float bias1 = expert_b[e1 * Oo + col];
#pragma unroll
    for (int m = 0; m < 4; ++m)
#pragma unroll
      for (int r = 0; r < 4; ++r) {
        const int row = m0 + wr * 64 + m * 16 + lg * 4 + r;
        const float v0 = acc0[m][n][r] + bias0;
        const float v1 = acc1[m][n][r] + bias1;
        const float ge0 = 0.5f * v0 * (1.0f + erff(v0 * 0.70710678118654752f));
        const float ge1 = 0.5f * v1 * (1.0f + erff(v1 * 0.70710678118654752f));
        out[(size_t)b * Ss * Oo + (size_t)row * Oo + col] = g0 * ge0 + g1 * ge1;
      }
  }
}

// ---------------------------------------------------------------------------
extern "C" void kernel_launch(void* const* d_in, const int* in_sizes, int n_in,
                              void* d_out, int out_size, void* d_ws, size_t ws_size,
                              hipStream_t stream) {
  const float* x        = (const float*)d_in[0];
  const float* gate_w   = (const float*)d_in[1];
  const float* gate_b   = (const float*)d_in[2];
  const float* expert_w = (const float*)d_in[3];
  const float* expert_b = (const float*)d_in[4];
  float* out = (float*)d_out;

  char* ws = (char*)d_ws;
  float* pooled = (float*)ws;                                   // B*D f32 = 32KB
  int*   eidx   = (int*)(ws + 32768);                           // B*2 ints
  float* egate  = (float*)(ws + 32768 + 4096);                  // B*2 floats
  unsigned short* xb = (unsigned short*)(ws + 65536);           // B*S*D bf16 = 32MB
  unsigned short* wb = (unsigned short*)(ws + 65536 + (size_t)Bb * Ss * Dd * 2);  // 16MB

  hipMemsetAsync(pooled, 0, Bb * Dd * sizeof(float), stream);

  k_convert_pool<<<dim3(64, Bb), 256, 0, stream>>>(x, xb, pooled);
  k_convert_w<<<(Ee * Oo * Dd) / (256 * 4), 256, 0, stream>>>(expert_w, wb);
  k_gates<<<1, 256, 0, stream>>>(pooled, gate_w, gate_b, eidx, egate);
  k_moe_gemm<<<(Ss / BM) * (Oo / BN) * Bb, 256, 0, stream>>>(xb, wb, eidx, egate,
                                                             expert_b, out);
}